// Round 1
// baseline (36649.188 us; speedup 1.0000x reference)
//
#include <hip/hip_runtime.h>
#include <stdint.h>

// ---------------------------------------------------------------------------
// Fused stochastic-interpolant SDE sampler.
//   out[s, obs, :] = 64 Euler-Maruyama steps of dX = (B + control) ds + sqrt(ds) eta
//   B = MLP(concat[x, x0, s]) 129->256->256->64, relu, fp32.
// One block = 16 observation rows for one sample chain; all 64 steps fused,
// X / X0 / activations live in LDS, weights streamed from L2.
// RNG: JAX threefry2x32 reproduced bit-exactly on device.
// ---------------------------------------------------------------------------

// JAX >= 0.4.36 defaults jax_threefry_partitionable=True (per-element 64-bit
// counter, 32-bit draw = bits1 ^ bits2; "foldlike" split). If the dataset was
// generated with the legacy scheme, absmax will come back ~5 (uncorrelated
// noise) -> flip this to 0.
#define PARTITIONABLE 1

namespace {

constexpr int   kObs    = 65536;
constexpr int   kDim    = 64;
constexpr int   kHid    = 256;
constexpr int   kSteps  = 64;
constexpr int   kTR     = 16;                       // rows per block
constexpr uint32_t kHalfElems = (uint32_t)kObs * kDim / 2;  // legacy pairing
constexpr float kDs     = 1.0f / 64.0f;
constexpr float kSqrtDs = 0.125f;

__device__ __forceinline__ uint32_t rotl(uint32_t v, int r) {
  return (v << r) | (v >> (32 - r));
}

// Threefry-2x32, 20 rounds, exactly as in jax/_src/prng.py.
__device__ __forceinline__ void tf2x32(uint32_t k0, uint32_t k1,
                                       uint32_t& x0, uint32_t& x1) {
  uint32_t k2 = k0 ^ k1 ^ 0x1BD11BDAu;
  x0 += k0; x1 += k1;
  x0 += x1; x1 = rotl(x1, 13); x1 ^= x0;
  x0 += x1; x1 = rotl(x1, 15); x1 ^= x0;
  x0 += x1; x1 = rotl(x1, 26); x1 ^= x0;
  x0 += x1; x1 = rotl(x1,  6); x1 ^= x0;
  x0 += k1; x1 += k2 + 1u;
  x0 += x1; x1 = rotl(x1, 17); x1 ^= x0;
  x0 += x1; x1 = rotl(x1, 29); x1 ^= x0;
  x0 += x1; x1 = rotl(x1, 16); x1 ^= x0;
  x0 += x1; x1 = rotl(x1, 24); x1 ^= x0;
  x0 += k2; x1 += k0 + 2u;
  x0 += x1; x1 = rotl(x1, 13); x1 ^= x0;
  x0 += x1; x1 = rotl(x1, 15); x1 ^= x0;
  x0 += x1; x1 = rotl(x1, 26); x1 ^= x0;
  x0 += x1; x1 = rotl(x1,  6); x1 ^= x0;
  x0 += k0; x1 += k1 + 3u;
  x0 += x1; x1 = rotl(x1, 17); x1 ^= x0;
  x0 += x1; x1 = rotl(x1, 29); x1 ^= x0;
  x0 += x1; x1 = rotl(x1, 16); x1 ^= x0;
  x0 += x1; x1 = rotl(x1, 24); x1 ^= x0;
  x0 += k1; x1 += k2 + 4u;
  x0 += x1; x1 = rotl(x1, 13); x1 ^= x0;
  x0 += x1; x1 = rotl(x1, 15); x1 ^= x0;
  x0 += x1; x1 = rotl(x1, 26); x1 ^= x0;
  x0 += x1; x1 = rotl(x1,  6); x1 ^= x0;
  x0 += k2; x1 += k0 + 5u;
}

// jax.random.split(key) -> child0=(a0,a1), child1=(b0,b1)
__device__ __forceinline__ void jax_split(uint32_t k0, uint32_t k1,
                                          uint32_t& a0, uint32_t& a1,
                                          uint32_t& b0, uint32_t& b1) {
#if PARTITIONABLE
  // foldlike: child_i = full cipher output of 64-bit counter i = (hi=0, lo=i)
  uint32_t x0 = 0u, x1 = 0u; tf2x32(k0, k1, x0, x1); a0 = x0; a1 = x1;
  uint32_t y0 = 0u, y1 = 1u; tf2x32(k0, k1, y0, y1); b0 = y0; b1 = y1;
#else
  // original: counts iota(4)=[0,1,2,3] -> pairs (0,2),(1,3);
  // child0 = (first words), child1 = (second words)
  uint32_t x0 = 0u, x1 = 2u; tf2x32(k0, k1, x0, x1);
  uint32_t y0 = 1u, y1 = 3u; tf2x32(k0, k1, y0, y1);
  a0 = x0; a1 = y0; b0 = x1; b1 = y1;
#endif
}

// 32 uniform bits for flat element index i of a (65536,64) draw.
__device__ __forceinline__ uint32_t draw_bits(uint32_t k0, uint32_t k1, uint32_t i) {
#if PARTITIONABLE
  uint32_t x0 = 0u, x1 = i;
  tf2x32(k0, k1, x0, x1);
  return x0 ^ x1;
#else
  if (i < kHalfElems) {
    uint32_t x0 = i, x1 = i + kHalfElems; tf2x32(k0, k1, x0, x1); return x0;
  } else {
    uint32_t x0 = i - kHalfElems, x1 = i; tf2x32(k0, k1, x0, x1); return x1;
  }
#endif
}

// XLA ErfInv32 (Giles 2012 rational approx) — must match lax.erf_inv on f32.
__device__ __forceinline__ float erfinv32(float x) {
  float w = -log1pf(-x * x);
  float p;
  if (w < 5.0f) {
    w = w - 2.5f;
    p =            2.81022636e-08f;
    p = fmaf(p, w, 3.43273939e-07f);
    p = fmaf(p, w, -3.5233877e-06f);
    p = fmaf(p, w, -4.39150654e-06f);
    p = fmaf(p, w, 0.00021858087f);
    p = fmaf(p, w, -0.00125372503f);
    p = fmaf(p, w, -0.00417768164f);
    p = fmaf(p, w, 0.246640727f);
    p = fmaf(p, w, 1.50140941f);
  } else {
    w = sqrtf(w) - 3.0f;
    p =            -0.000200214257f;
    p = fmaf(p, w, 0.000100950558f);
    p = fmaf(p, w, 0.00134934322f);
    p = fmaf(p, w, -0.00367342844f);
    p = fmaf(p, w, 0.00573950773f);
    p = fmaf(p, w, -0.0076224613f);
    p = fmaf(p, w, 0.00943887047f);
    p = fmaf(p, w, 1.00167406f);
    p = fmaf(p, w, 2.83297682f);
  }
  return p * x;
}

// jax.random.normal: u ~ uniform[nextafter(-1,0), 1), z = sqrt(2)*erfinv(u).
// (maxval-minval) rounds to exactly 2.0f in fp32.
__device__ __forceinline__ float bits_to_normal(uint32_t bits) {
  const float lo = -0.99999994f;                       // nextafter(-1,0)
  float f = __uint_as_float(0x3f800000u | (bits >> 9)) - 1.0f;  // [0,1)
  float u = fmaxf(lo, fmaf(f, 2.0f, lo));
  return 1.41421356237f * erfinv32(u);                 // 0x3FB504F3
}

}  // namespace

__global__ __launch_bounds__(256, 3)
void sde_sampler(const float* __restrict__ X0g,
                 const float* __restrict__ W1, const float* __restrict__ b1,
                 const float* __restrict__ W2, const float* __restrict__ b2,
                 const float* __restrict__ W3, const float* __restrict__ b3,
                 float* __restrict__ out) {
  // LDS: 3*4KB + 2*16KB = 44KB -> 3 blocks/CU (12 waves).
  __shared__ float sX [kTR][kDim];
  __shared__ float sX0[kTR][kDim];
  __shared__ float sH1[kTR][kHid];
  __shared__ float sH2[kTR][kHid];
  __shared__ float sO [kTR][kDim];

  const int t    = threadIdx.x;
  const int samp = blockIdx.x >> 12;   // 4096 blocks per sample chain
  const int tile = blockIdx.x & 4095;
  const int r0   = tile * kTR;         // first observation row of this tile

  // ---- load X0 tile (16 rows x 64 cols, float4-coalesced) ----
  {
    const int r = t >> 4, c = (t & 15) << 2;
    const float4 v =
        *reinterpret_cast<const float4*>(X0g + (size_t)(r0 + r) * kDim + c);
    *reinterpret_cast<float4*>(&sX0[r][c]) = v;
    *reinterpret_cast<float4*>(&sX [r][c]) = v;
  }

  // ---- loop-invariant preloads (thread j owns neuron j for L1/L2) ----
  const int   j    = t;
  const float b1j  = b1[j];
  const float w1sj = W1[128 * kHid + j];   // the `s`-column of W1
  const float b2j  = b2[j];
  const int   j3   = t & 63;               // L3 neuron
  const int   rg   = t >> 6;               // L3 row group (4 rows each)
  const float b3j  = b3[j3];

  // ---- RNG key chain (wave-uniform, constant-seed) ----
  // root = key(1) = (0,1); split -> 2 sample keys; split -> (draw0, loop).
  uint32_t s0a, s0b, s1a, s1b;
  jax_split(0u, 1u, s0a, s0b, s1a, s1b);
  const uint32_t sk0 = samp ? s1a : s0a;
  const uint32_t sk1 = samp ? s1b : s0b;
  uint32_t kd0, kd1, kl0, kl1;
  jax_split(sk0, sk1, kd0, kd1, kl0, kl1);

  __syncthreads();

  // ---- c0[r] = b1 + x0 @ W1[64:128]  (step-invariant half of layer 1) ----
  float c0[kTR];
#pragma unroll
  for (int r = 0; r < kTR; ++r) c0[r] = b1j;
#pragma unroll 4
  for (int d = 0; d < kDim; d += 4) {
    const float wa = W1[(64 + d + 0) * kHid + j];
    const float wb = W1[(64 + d + 1) * kHid + j];
    const float wc = W1[(64 + d + 2) * kHid + j];
    const float wd = W1[(64 + d + 3) * kHid + j];
#pragma unroll
    for (int r = 0; r < kTR; ++r) {
      const float4 xv = *reinterpret_cast<const float4*>(&sX0[r][d]);
      c0[r] = fmaf(xv.x, wa, c0[r]);
      c0[r] = fmaf(xv.y, wb, c0[r]);
      c0[r] = fmaf(xv.z, wc, c0[r]);
      c0[r] = fmaf(xv.w, wd, c0[r]);
    }
  }

  float acc[kTR];
  for (int n = 0; n < kSteps; ++n) {
    const float s = (float)n * kDs;   // exact n/64

    // ---------------- layer 1: h1 = relu(x@W1a + c0 + s*w1s) ----------------
#pragma unroll
    for (int r = 0; r < kTR; ++r) acc[r] = fmaf(s, w1sj, c0[r]);
#pragma unroll 4
    for (int d = 0; d < kDim; d += 4) {
      const float wa = W1[(d + 0) * kHid + j];
      const float wb = W1[(d + 1) * kHid + j];
      const float wc = W1[(d + 2) * kHid + j];
      const float wd = W1[(d + 3) * kHid + j];
#pragma unroll
      for (int r = 0; r < kTR; ++r) {
        const float4 xv = *reinterpret_cast<const float4*>(&sX[r][d]);
        acc[r] = fmaf(xv.x, wa, acc[r]);
        acc[r] = fmaf(xv.y, wb, acc[r]);
        acc[r] = fmaf(xv.z, wc, acc[r]);
        acc[r] = fmaf(xv.w, wd, acc[r]);
      }
    }
#pragma unroll
    for (int r = 0; r < kTR; ++r) sH1[r][j] = fmaxf(acc[r], 0.0f);
    __syncthreads();

    // ---------------- layer 2: h2 = relu(h1@W2 + b2) ----------------
#pragma unroll
    for (int r = 0; r < kTR; ++r) acc[r] = b2j;
#pragma unroll 4
    for (int d = 0; d < kHid; d += 4) {
      const float wa = W2[(d + 0) * kHid + j];
      const float wb = W2[(d + 1) * kHid + j];
      const float wc = W2[(d + 2) * kHid + j];
      const float wd = W2[(d + 3) * kHid + j];
#pragma unroll
      for (int r = 0; r < kTR; ++r) {
        const float4 hv = *reinterpret_cast<const float4*>(&sH1[r][d]);
        acc[r] = fmaf(hv.x, wa, acc[r]);
        acc[r] = fmaf(hv.y, wb, acc[r]);
        acc[r] = fmaf(hv.z, wc, acc[r]);
        acc[r] = fmaf(hv.w, wd, acc[r]);
      }
    }
#pragma unroll
    for (int r = 0; r < kTR; ++r) sH2[r][j] = fmaxf(acc[r], 0.0f);
    __syncthreads();

    // ---------------- layer 3: drift = h2@W3 + b3 ----------------
    float a3[4];
#pragma unroll
    for (int q = 0; q < 4; ++q) a3[q] = b3j;
#pragma unroll 4
    for (int d = 0; d < kHid; d += 4) {
      const float wa = W3[(d + 0) * kDim + j3];
      const float wb = W3[(d + 1) * kDim + j3];
      const float wc = W3[(d + 2) * kDim + j3];
      const float wd = W3[(d + 3) * kDim + j3];
#pragma unroll
      for (int q = 0; q < 4; ++q) {
        const float4 hv = *reinterpret_cast<const float4*>(&sH2[rg * 4 + q][d]);
        a3[q] = fmaf(hv.x, wa, a3[q]);
        a3[q] = fmaf(hv.y, wb, a3[q]);
        a3[q] = fmaf(hv.z, wc, a3[q]);
        a3[q] = fmaf(hv.w, wd, a3[q]);
      }
    }
#pragma unroll
    for (int q = 0; q < 4; ++q) sO[rg * 4 + q][j3] = a3[q];
    __syncthreads();

    // ---------------- per-step draw key ----------------
    uint32_t ka, kb;
    if (n == 0) {
      ka = kd0; kb = kd1;                      // first Euler step uses k0
    } else {
      uint32_t na, nb, xa, xb;
      jax_split(kl0, kl1, na, nb, xa, xb);     // key, kn = split(key)
      kl0 = na; kl1 = nb; ka = xa; kb = xb;
    }

    // score coefficients (all exact dyadics in fp32 except the division):
    //   c = X - X0; A = 1/(s(1-s)); control = 0.5(1-(1-s)^2) * A * (s*drift - c)
    const float sg   = 1.0f - s;
    const float A    = (n == 0) ? 0.0f : 1.0f / (s * sg);
    const float coef = 0.5f * (1.0f - sg * sg);   // == 0 at n==0

    // ---------------- update X (+ fresh Gaussian noise) ----------------
#pragma unroll
    for (int k = 0; k < (kTR * kDim) / 256; ++k) {
      const int e  = t + k * 256;
      const int li = e >> 6;
      const int d  = e & 63;
      const uint32_t gi = (uint32_t)((r0 + li) * kDim + d);
      const float eta  = bits_to_normal(draw_bits(ka, kb, gi));
      const float Xv   = sX[li][d];
      const float X0v  = sX0[li][d];
      const float dr   = sO[li][d];
      const float score = A * (s * dr - (Xv - X0v));
      const float ctrl  = coef * score;
      sX[li][d] = Xv + kDs * (dr + ctrl) + kSqrtDs * eta;
    }
    __syncthreads();
  }

  // ---- write result tile ----
  {
    const int r = t >> 4, c = (t & 15) << 2;
    const size_t o = (size_t)samp * ((size_t)kObs * kDim) +
                     (size_t)(r0 + r) * kDim + c;
    *reinterpret_cast<float4*>(out + o) =
        *reinterpret_cast<const float4*>(&sX[r][c]);
  }
}

extern "C" void kernel_launch(void* const* d_in, const int* in_sizes, int n_in,
                              void* d_out, int out_size, void* d_ws, size_t ws_size,
                              hipStream_t stream) {
  const float* X0 = (const float*)d_in[0];
  const float* W1 = (const float*)d_in[1];
  const float* b1 = (const float*)d_in[2];
  const float* W2 = (const float*)d_in[3];
  const float* b2 = (const float*)d_in[4];
  const float* W3 = (const float*)d_in[5];
  const float* b3 = (const float*)d_in[6];
  float* outp = (float*)d_out;

  // 2 samples x (65536/16) tiles = 8192 blocks, 256 threads.
  sde_sampler<<<dim3(8192), dim3(256), 0, stream>>>(X0, W1, b1, W2, b2, W3, b3,
                                                    outp);
}

// Round 2
// 5705.037 us; speedup vs baseline: 6.4240x; 6.4240x over previous
//
#include <hip/hip_runtime.h>
#include <stdint.h>

// ---------------------------------------------------------------------------
// Fused SDE sampler, round 2: f16 MFMA (16x16x32, fp32 accum) for the MLP.
//   - 32 rows/block, 4 waves; wave w owns neurons [64w,64w+64) for BOTH
//     16-row M-tiles -> every B-fragment load feeds 2 MFMAs, no redundancy.
//   - Weights pre-packed to MFMA B-fragment order (f16) in d_ws by prep
//     kernel; main loop does coalesced dwordx4 loads from L2.
//   - Activations staged in LDS f16, row-padded (+8 f16 -> 2-way banks, free).
//   - Layer 1 runs K=128 (x | x0), bias + s*W1[128] folded into epilogue.
//   - RNG identical to round 1 (bit-exact JAX threefry, verified).
// ---------------------------------------------------------------------------

#define PARTITIONABLE 1

namespace {

constexpr int   kObs    = 65536;
constexpr int   kDim    = 64;
constexpr int   kSteps  = 64;
constexpr float kDs     = 1.0f / 64.0f;
constexpr float kSqrtDs = 0.125f;

typedef _Float16 f16x8 __attribute__((ext_vector_type(8)));
typedef float    f32x4 __attribute__((ext_vector_type(4)));

#define MFMA16(a, b, c) __builtin_amdgcn_mfma_f32_16x16x32_f16((a), (b), (c), 0, 0, 0)

__device__ __forceinline__ uint32_t rotl(uint32_t v, int r) {
  return (v << r) | (v >> (32 - r));
}

__device__ __forceinline__ void tf2x32(uint32_t k0, uint32_t k1,
                                       uint32_t& x0, uint32_t& x1) {
  uint32_t k2 = k0 ^ k1 ^ 0x1BD11BDAu;
  x0 += k0; x1 += k1;
  x0 += x1; x1 = rotl(x1, 13); x1 ^= x0;
  x0 += x1; x1 = rotl(x1, 15); x1 ^= x0;
  x0 += x1; x1 = rotl(x1, 26); x1 ^= x0;
  x0 += x1; x1 = rotl(x1,  6); x1 ^= x0;
  x0 += k1; x1 += k2 + 1u;
  x0 += x1; x1 = rotl(x1, 17); x1 ^= x0;
  x0 += x1; x1 = rotl(x1, 29); x1 ^= x0;
  x0 += x1; x1 = rotl(x1, 16); x1 ^= x0;
  x0 += x1; x1 = rotl(x1, 24); x1 ^= x0;
  x0 += k2; x1 += k0 + 2u;
  x0 += x1; x1 = rotl(x1, 13); x1 ^= x0;
  x0 += x1; x1 = rotl(x1, 15); x1 ^= x0;
  x0 += x1; x1 = rotl(x1, 26); x1 ^= x0;
  x0 += x1; x1 = rotl(x1,  6); x1 ^= x0;
  x0 += k0; x1 += k1 + 3u;
  x0 += x1; x1 = rotl(x1, 17); x1 ^= x0;
  x0 += x1; x1 = rotl(x1, 29); x1 ^= x0;
  x0 += x1; x1 = rotl(x1, 16); x1 ^= x0;
  x0 += x1; x1 = rotl(x1, 24); x1 ^= x0;
  x0 += k1; x1 += k2 + 4u;
  x0 += x1; x1 = rotl(x1, 13); x1 ^= x0;
  x0 += x1; x1 = rotl(x1, 15); x1 ^= x0;
  x0 += x1; x1 = rotl(x1, 26); x1 ^= x0;
  x0 += x1; x1 = rotl(x1,  6); x1 ^= x0;
  x0 += k2; x1 += k0 + 5u;
}

__device__ __forceinline__ void jax_split(uint32_t k0, uint32_t k1,
                                          uint32_t& a0, uint32_t& a1,
                                          uint32_t& b0, uint32_t& b1) {
#if PARTITIONABLE
  uint32_t x0 = 0u, x1 = 0u; tf2x32(k0, k1, x0, x1); a0 = x0; a1 = x1;
  uint32_t y0 = 0u, y1 = 1u; tf2x32(k0, k1, y0, y1); b0 = y0; b1 = y1;
#else
  uint32_t x0 = 0u, x1 = 2u; tf2x32(k0, k1, x0, x1);
  uint32_t y0 = 1u, y1 = 3u; tf2x32(k0, k1, y0, y1);
  a0 = x0; a1 = y0; b0 = x1; b1 = y1;
#endif
}

__device__ __forceinline__ uint32_t draw_bits(uint32_t k0, uint32_t k1, uint32_t i) {
#if PARTITIONABLE
  uint32_t x0 = 0u, x1 = i;
  tf2x32(k0, k1, x0, x1);
  return x0 ^ x1;
#else
  const uint32_t half = (uint32_t)kObs * kDim / 2;
  if (i < half) {
    uint32_t x0 = i, x1 = i + half; tf2x32(k0, k1, x0, x1); return x0;
  } else {
    uint32_t x0 = i - half, x1 = i; tf2x32(k0, k1, x0, x1); return x1;
  }
#endif
}

__device__ __forceinline__ float erfinv32(float x) {
  float w = -log1pf(-x * x);
  float p;
  if (w < 5.0f) {
    w = w - 2.5f;
    p =            2.81022636e-08f;
    p = fmaf(p, w, 3.43273939e-07f);
    p = fmaf(p, w, -3.5233877e-06f);
    p = fmaf(p, w, -4.39150654e-06f);
    p = fmaf(p, w, 0.00021858087f);
    p = fmaf(p, w, -0.00125372503f);
    p = fmaf(p, w, -0.00417768164f);
    p = fmaf(p, w, 0.246640727f);
    p = fmaf(p, w, 1.50140941f);
  } else {
    w = sqrtf(w) - 3.0f;
    p =            -0.000200214257f;
    p = fmaf(p, w, 0.000100950558f);
    p = fmaf(p, w, 0.00134934322f);
    p = fmaf(p, w, -0.00367342844f);
    p = fmaf(p, w, 0.00573950773f);
    p = fmaf(p, w, -0.0076224613f);
    p = fmaf(p, w, 0.00943887047f);
    p = fmaf(p, w, 1.00167406f);
    p = fmaf(p, w, 2.83297682f);
  }
  return p * x;
}

__device__ __forceinline__ float bits_to_normal(uint32_t bits) {
  const float lo = -0.99999994f;
  float f = __uint_as_float(0x3f800000u | (bits >> 9)) - 1.0f;
  float u = fmaxf(lo, fmaf(f, 2.0f, lo));
  return 1.41421356237f * erfinv32(u);
}

}  // namespace

// ---------------------------------------------------------------------------
// Weight prep: convert fp32 weights to f16 MFMA B-fragments in d_ws.
// Tile = 16(N) x 32(K) fragment = 1024 B; lane l holds B[k=(l>>4)*8+j][n=l&15].
// Tile order matches main kernel's per-wave load order:
//   L1 : tiles [  0, 64) : id =       w*16 + nt*4 + kt   (K=128: x|x0 rows of W1)
//   L2 : tiles [ 64,192) : id =  64 + w*32 + nt*8 + kt
//   L3 : tiles [192,224) : id = 192 + w*8  + kt          (ntile == w)
// ---------------------------------------------------------------------------
__global__ void prep_weights(const float* __restrict__ W1,
                             const float* __restrict__ W2,
                             const float* __restrict__ W3,
                             _Float16* __restrict__ ws) {
  const int tile = blockIdx.x;
  const int t    = threadIdx.x;
  const int lane = t >> 2;
  const int j0   = (t & 3) * 2;

  int layer, w, nt, kt;
  if (tile < 64)       { layer = 1; w = tile >> 4;      nt = (tile >> 2) & 3; kt = tile & 3; }
  else if (tile < 192) { int u = tile - 64;  layer = 2; w = u >> 5; nt = (u >> 3) & 3; kt = u & 7; }
  else                 { int u = tile - 192; layer = 3; w = u >> 3; nt = 0;           kt = u & 7; }

  const int col = (layer == 3) ? (w * 16 + (lane & 15))
                               : ((w * 4 + nt) * 16 + (lane & 15));
#pragma unroll
  for (int jj = 0; jj < 2; ++jj) {
    const int j = j0 + jj;
    const int k = kt * 32 + ((lane >> 4) << 3) + j;
    float v;
    if (layer == 1)      v = W1[k * 256 + col];   // rows 0..127 of W1 (x|x0)
    else if (layer == 2) v = W2[k * 256 + col];
    else                 v = W3[k * 64  + col];
    ws[(size_t)tile * 512 + lane * 8 + j] = (_Float16)v;
  }
}

// ---------------------------------------------------------------------------
// Main fused kernel.
// ---------------------------------------------------------------------------
__global__ __launch_bounds__(256, 2)
void sde_mfma(const float* __restrict__ X0g,
              const float* __restrict__ W1,
              const float* __restrict__ b1,
              const float* __restrict__ b2,
              const float* __restrict__ b3,
              const _Float16* __restrict__ ws,
              float* __restrict__ out) {
  // LDS: 2*8.7K fp32 + 2*4.6K f16 + 2*16.9K f16 = 60.4 KB -> 2 blocks/CU.
  __shared__ alignas(16) float    sX [32][68];
  __shared__ alignas(16) float    sX0[32][68];
  __shared__ alignas(16) _Float16 xA [32][72];   // f16 copy of X, A-frag friendly
  __shared__ alignas(16) _Float16 x0A[32][72];
  __shared__ alignas(16) _Float16 h1 [32][264];
  __shared__ alignas(16) _Float16 h2 [32][264];
  // drift output overlays h1 (dead by the time L3 writes it)
  float (*sO)[68] = reinterpret_cast<float (*)[68]>(&h1[0][0]);

  const int t  = threadIdx.x;
  const int w  = t >> 6;          // wave id: owns neurons [64w, 64w+64)
  const int l  = t & 63;
  const int lq = l >> 4;          // quad
  const int lm = l & 15;
  const int samp = blockIdx.x >> 11;       // 2048 blocks per sample
  const int tile = blockIdx.x & 2047;
  const int r0   = tile * 32;

  const int li = t >> 3;          // update-phase row (0..31)
  const int ci = (t & 7) * 8;     // update-phase col base

  // ---- load X0 tile ----
  {
    const float* p = X0g + (size_t)(r0 + li) * kDim + ci;
    const float4 v0 = *(const float4*)p;
    const float4 v1 = *(const float4*)(p + 4);
    *(float4*)&sX0[li][ci]     = v0;
    *(float4*)&sX0[li][ci + 4] = v1;
    *(float4*)&sX [li][ci]     = v0;
    *(float4*)&sX [li][ci + 4] = v1;
    f16x8 hx;
    hx[0] = (_Float16)v0.x; hx[1] = (_Float16)v0.y;
    hx[2] = (_Float16)v0.z; hx[3] = (_Float16)v0.w;
    hx[4] = (_Float16)v1.x; hx[5] = (_Float16)v1.y;
    hx[6] = (_Float16)v1.z; hx[7] = (_Float16)v1.w;
    *(f16x8*)&xA [li][ci] = hx;
    *(f16x8*)&x0A[li][ci] = hx;
  }

  // ---- per-wave bias preloads (lane's column per N-tile) ----
  float b1v[4], w1sv[4], b2v[4];
#pragma unroll
  for (int nt = 0; nt < 4; ++nt) {
    const int nn = (w * 4 + nt) * 16 + lm;
    b1v[nt]  = b1[nn];
    w1sv[nt] = W1[128 * 256 + nn];   // s-row of W1
    b2v[nt]  = b2[nn];
  }
  const float b3v = b3[w * 16 + lm];

  // ---- B-fragment base pointers ----
  const char* wsB = (const char*)ws;
  const char* pB1 = wsB + (size_t)w * 16 * 1024;
  const char* pB2 = wsB + 64 * 1024  + (size_t)w * 32 * 1024;
  const char* pB3 = wsB + 192 * 1024 + (size_t)w * 8 * 1024;
  const int lb = l * 16;

  // ---- RNG key chain (identical to verified round-1) ----
  uint32_t s0a, s0b, s1a, s1b;
  jax_split(0u, 1u, s0a, s0b, s1a, s1b);
  const uint32_t sk0 = samp ? s1a : s0a;
  const uint32_t sk1 = samp ? s1b : s0b;
  uint32_t kd0, kd1, kl0, kl1;
  jax_split(sk0, sk1, kd0, kd1, kl0, kl1);

  __syncthreads();

  for (int n = 0; n < kSteps; ++n) {
    const float s = (float)n * kDs;

    // ================= layer 1 (K=128: x | x0) =================
    f16x8 aX[2][4];
#pragma unroll
    for (int mt = 0; mt < 2; ++mt) {
      const int row = mt * 16 + lm;
#pragma unroll
      for (int k2 = 0; k2 < 2; ++k2) {
        aX[mt][k2]     = *(const f16x8*)&xA [row][k2 * 32 + lq * 8];
        aX[mt][k2 + 2] = *(const f16x8*)&x0A[row][k2 * 32 + lq * 8];
      }
    }
#pragma unroll
    for (int nt = 0; nt < 4; ++nt) {
      f32x4 c0 = {0.f, 0.f, 0.f, 0.f}, c1 = {0.f, 0.f, 0.f, 0.f};
#pragma unroll
      for (int kt = 0; kt < 4; ++kt) {
        const f16x8 bf = *(const f16x8*)(pB1 + (nt * 4 + kt) * 1024 + lb);
        c0 = MFMA16(aX[0][kt], bf, c0);
        c1 = MFMA16(aX[1][kt], bf, c1);
      }
      const float be = fmaf(s, w1sv[nt], b1v[nt]);
      const int nc = (w * 4 + nt) * 16 + lm;
#pragma unroll
      for (int q = 0; q < 4; ++q) {
        h1[lq * 4 + q][nc]      = (_Float16)fmaxf(c0[q] + be, 0.f);
        h1[16 + lq * 4 + q][nc] = (_Float16)fmaxf(c1[q] + be, 0.f);
      }
    }
    __syncthreads();

    // ================= layer 2 (K=256) =================
    f16x8 aH[2][8];
#pragma unroll
    for (int mt = 0; mt < 2; ++mt)
#pragma unroll
      for (int kt = 0; kt < 8; ++kt)
        aH[mt][kt] = *(const f16x8*)&h1[mt * 16 + lm][kt * 32 + lq * 8];
#pragma unroll
    for (int nt = 0; nt < 4; ++nt) {
      f32x4 c0 = {0.f, 0.f, 0.f, 0.f}, c1 = {0.f, 0.f, 0.f, 0.f};
#pragma unroll
      for (int kt = 0; kt < 8; ++kt) {
        const f16x8 bf = *(const f16x8*)(pB2 + (nt * 8 + kt) * 1024 + lb);
        c0 = MFMA16(aH[0][kt], bf, c0);
        c1 = MFMA16(aH[1][kt], bf, c1);
      }
      const int nc = (w * 4 + nt) * 16 + lm;
#pragma unroll
      for (int q = 0; q < 4; ++q) {
        h2[lq * 4 + q][nc]      = (_Float16)fmaxf(c0[q] + b2v[nt], 0.f);
        h2[16 + lq * 4 + q][nc] = (_Float16)fmaxf(c1[q] + b2v[nt], 0.f);
      }
    }
    __syncthreads();

    // ================= layer 3 (K=256, N=64; wave w -> ntile w) =================
#pragma unroll
    for (int mt = 0; mt < 2; ++mt)
#pragma unroll
      for (int kt = 0; kt < 8; ++kt)
        aH[mt][kt] = *(const f16x8*)&h2[mt * 16 + lm][kt * 32 + lq * 8];
    f32x4 d0 = {0.f, 0.f, 0.f, 0.f}, d1 = {0.f, 0.f, 0.f, 0.f};
#pragma unroll
    for (int kt = 0; kt < 8; ++kt) {
      const f16x8 bf = *(const f16x8*)(pB3 + kt * 1024 + lb);
      d0 = MFMA16(aH[0][kt], bf, d0);
      d1 = MFMA16(aH[1][kt], bf, d1);
    }
    const int nc3 = w * 16 + lm;
#pragma unroll
    for (int q = 0; q < 4; ++q) {
      sO[lq * 4 + q][nc3]      = d0[q] + b3v;
      sO[16 + lq * 4 + q][nc3] = d1[q] + b3v;
    }
    __syncthreads();

    // ================= Euler-Maruyama update =================
    uint32_t ka, kb;
    if (n == 0) {
      ka = kd0; kb = kd1;
    } else {
      uint32_t na, nb, xa, xb;
      jax_split(kl0, kl1, na, nb, xa, xb);
      kl0 = na; kl1 = nb; ka = xa; kb = xb;
    }
    const float sg   = 1.0f - s;
    const float A    = (n == 0) ? 0.0f : 1.0f / (s * sg);
    const float coef = 0.5f * (1.0f - sg * sg);

    const float4 xva  = *(const float4*)&sX [li][ci];
    const float4 xvb  = *(const float4*)&sX [li][ci + 4];
    const float4 x0a  = *(const float4*)&sX0[li][ci];
    const float4 x0b  = *(const float4*)&sX0[li][ci + 4];
    const float4 ova  = *(const float4*)&sO [li][ci];
    const float4 ovb  = *(const float4*)&sO [li][ci + 4];
    const float xv[8]  = {xva.x, xva.y, xva.z, xva.w, xvb.x, xvb.y, xvb.z, xvb.w};
    const float x0v[8] = {x0a.x, x0a.y, x0a.z, x0a.w, x0b.x, x0b.y, x0b.z, x0b.w};
    const float ov[8]  = {ova.x, ova.y, ova.z, ova.w, ovb.x, ovb.y, ovb.z, ovb.w};
    float nx[8];
    f16x8 hx;
#pragma unroll
    for (int j = 0; j < 8; ++j) {
      const uint32_t gi = (uint32_t)((r0 + li) * kDim + ci + j);
      const float eta   = bits_to_normal(draw_bits(ka, kb, gi));
      const float score = A * (s * ov[j] - (xv[j] - x0v[j]));
      nx[j] = xv[j] + kDs * (ov[j] + coef * score) + kSqrtDs * eta;
      hx[j] = (_Float16)nx[j];
    }
    *(float4*)&sX[li][ci]     = make_float4(nx[0], nx[1], nx[2], nx[3]);
    *(float4*)&sX[li][ci + 4] = make_float4(nx[4], nx[5], nx[6], nx[7]);
    *(f16x8*)&xA[li][ci] = hx;
    __syncthreads();
  }

  // ---- write result tile ----
  const size_t ob = (size_t)samp * ((size_t)kObs * kDim) +
                    (size_t)(r0 + li) * kDim + ci;
  *(float4*)(out + ob)     = *(const float4*)&sX[li][ci];
  *(float4*)(out + ob + 4) = *(const float4*)&sX[li][ci + 4];
}

extern "C" void kernel_launch(void* const* d_in, const int* in_sizes, int n_in,
                              void* d_out, int out_size, void* d_ws, size_t ws_size,
                              hipStream_t stream) {
  const float* X0 = (const float*)d_in[0];
  const float* W1 = (const float*)d_in[1];
  const float* b1 = (const float*)d_in[2];
  const float* W2 = (const float*)d_in[3];
  const float* b2 = (const float*)d_in[4];
  const float* W3 = (const float*)d_in[5];
  const float* b3 = (const float*)d_in[6];
  _Float16* ws = (_Float16*)d_ws;   // 224 KB of B-fragments

  prep_weights<<<dim3(224), dim3(256), 0, stream>>>(W1, W2, W3, ws);
  sde_mfma<<<dim3(4096), dim3(256), 0, stream>>>(X0, W1, b1, b2, b3, ws,
                                                 (float*)d_out);
}